// Round 2
// baseline (90.339 us; speedup 1.0000x reference)
//
#include <hip/hip_runtime.h>
#include <hip/hip_bf16.h>
#include <stdint.h>

typedef __attribute__((ext_vector_type(8))) short short8;
typedef __attribute__((ext_vector_type(4))) float f32x4;

#define BSZ 512
#define DFIELD 16384
#define KSPLIT 96
#define KCHUNK 512
#define BK 64
#define NTILE 10
#define NPAIRS 130816.0f
#define PSLICE (BSZ * BSZ)

__device__ __forceinline__ ushort f2bf(float f) {
    uint32_t u = __float_as_uint(f);
    uint32_t r = (u + 0x7fffu + ((u >> 16) & 1u)) >> 16;
    return (ushort)r;
}

__device__ __forceinline__ float bf2f(ushort u) {
    return __uint_as_float(((uint32_t)u) << 16);
}

// 4 fp32 -> 4 bf16 (packed in uint2) via 2 HW pack-converts
__device__ __forceinline__ uint2 cvt_f4(float4 v) {
    uint2 r;
    asm("v_cvt_pk_bf16_f32 %0, %1, %2" : "=v"(r.x) : "v"(v.x), "v"(v.y));
    asm("v_cvt_pk_bf16_f32 %0, %1, %2" : "=v"(r.y) : "v"(v.z), "v"(v.w));
    return r;
}

__global__ __launch_bounds__(256) void gemm_kernel(
    const float* __restrict__ e, const float* __restrict__ a,
    const float* __restrict__ c, ushort* __restrict__ P) {
    const int tile = blockIdx.x / KSPLIT;
    const int ks   = blockIdx.x % KSPLIT;
    // linear tile -> (ti, tj) upper triangle incl. diagonal, 4x4 tile grid
    int ti = 0, rem = tile;
    while (rem >= 4 - ti) { rem -= 4 - ti; ++ti; }
    const int tj = ti + rem;
    const bool diag = (ti == tj);
    const int brow = ti * 128, bcol = tj * 128;

    const int kbase = ks * KCHUNK;
    const int field = kbase / DFIELD;
    const int koff0 = kbase % DFIELD;
    const float* X = (field == 0) ? e : ((field == 1) ? a : c);

    __shared__ ushort As[128 * 64];
    __shared__ ushort Bs[128 * 64];

    const int t = threadIdx.x;
    const int lane = t & 63, wid = t >> 6;
    const int wr = (wid >> 1) * 64, wc = (wid & 1) * 64;
    const int srow = t >> 3;          // 0..31
    const int scg  = (t & 7) * 8;     // k offset within BK (8-elem granules)

    const f32x4 zero = {0.f, 0.f, 0.f, 0.f};
    f32x4 acc[4][4];
#pragma unroll
    for (int m = 0; m < 4; ++m)
#pragma unroll
        for (int n = 0; n < 4; ++n) acc[m][n] = zero;

    const float* pa = X + (size_t)(brow + srow) * DFIELD + koff0 + scg;
    const float* pb = X + (size_t)(bcol + srow) * DFIELD + koff0 + scg;

    for (int kt = 0; kt < KCHUNK / BK; ++kt) {
        const int kk = kt * BK;
        // ---- stage A (fp32 -> bf16 via v_cvt_pk_bf16_f32) ----
#pragma unroll
        for (int rep = 0; rep < 4; ++rep) {
            const int r = srow + rep * 32;
            const float* p = pa + (size_t)(rep * 32) * DFIELD + kk;
            float4 v0 = reinterpret_cast<const float4*>(p)[0];
            float4 v1 = reinterpret_cast<const float4*>(p)[1];
            uint2 w0 = cvt_f4(v0);
            uint2 w1 = cvt_f4(v1);
            uint4 w = {w0.x, w0.y, w1.x, w1.y};
            const int g = (scg >> 3) ^ (r & 7);
            *reinterpret_cast<uint4*>(&As[r * 64 + g * 8]) = w;
        }
        // ---- stage B (skipped on diagonal tiles: A == B) ----
        if (!diag) {
#pragma unroll
            for (int rep = 0; rep < 4; ++rep) {
                const int r = srow + rep * 32;
                const float* p = pb + (size_t)(rep * 32) * DFIELD + kk;
                float4 v0 = reinterpret_cast<const float4*>(p)[0];
                float4 v1 = reinterpret_cast<const float4*>(p)[1];
                uint2 w0 = cvt_f4(v0);
                uint2 w1 = cvt_f4(v1);
                uint4 w = {w0.x, w0.y, w1.x, w1.y};
                const int g = (scg >> 3) ^ (r & 7);
                *reinterpret_cast<uint4*>(&Bs[r * 64 + g * 8]) = w;
            }
        }
        __syncthreads();
        // ---- compute ----
        const ushort* Bsrc = diag ? As : Bs;
#pragma unroll
        for (int half = 0; half < 2; ++half) {
            short8 af[4], bfv[4];
            const int kq = half * 4 + (lane >> 4);  // 16B granule (pre-swizzle)
#pragma unroll
            for (int m = 0; m < 4; ++m) {
                const int row = wr + m * 16 + (lane & 15);
                const int g = kq ^ (row & 7);
                af[m] = *reinterpret_cast<const short8*>(&As[row * 64 + g * 8]);
            }
#pragma unroll
            for (int n = 0; n < 4; ++n) {
                const int row = wc + n * 16 + (lane & 15);
                const int g = kq ^ (row & 7);
                bfv[n] = *reinterpret_cast<const short8*>(&Bsrc[row * 64 + g * 8]);
            }
#pragma unroll
            for (int m = 0; m < 4; ++m)
#pragma unroll
                for (int n = 0; n < 4; ++n)
                    acc[m][n] = __builtin_amdgcn_mfma_f32_16x16x32_bf16(
                        af[m], bfv[n], acc[m][n], 0, 0, 0);
        }
        __syncthreads();
    }

    // ---- write split-K partials as bf16 (deterministic, no atomics) ----
    ushort* Pk = P + (size_t)ks * PSLICE;
    const int ci = (lane >> 4) * 4;  // C/D layout: row = (lane>>4)*4 + reg
    const int cj = lane & 15;        //             col = lane & 15
#pragma unroll
    for (int m = 0; m < 4; ++m)
#pragma unroll
        for (int n = 0; n < 4; ++n)
#pragma unroll
            for (int r = 0; r < 4; ++r) {
                const int gi = brow + wr + m * 16 + ci + r;
                const int gj = bcol + wc + n * 16 + cj;
                Pk[(size_t)gi * BSZ + gj] = f2bf(acc[m][n][r]);
            }
}

__global__ void diag_kernel(const ushort* __restrict__ P, float* __restrict__ DIAG) {
    int i = blockIdx.x * blockDim.x + threadIdx.x;
    if (i < BSZ) {
        float s = 0.f;
        for (int k = 0; k < KSPLIT; ++k)
            s += bf2f(P[(size_t)k * PSLICE + (size_t)i * BSZ + i]);
        DIAG[i] = s;
    }
}

__global__ __launch_bounds__(256) void pair_kernel(
    const ushort* __restrict__ P, const float* __restrict__ DIAG,
    const int* __restrict__ tg, float* __restrict__ LP) {
    const int t = threadIdx.x;
    const int p = blockIdx.x * 256 + t;   // one pair per thread, 1024 blocks
    const int i = p >> 9, j = p & 511;
    float local = 0.f;
    if (i < j) {
        float g = 0.f;
        for (int k = 0; k < KSPLIT; ++k)
            g += bf2f(P[(size_t)k * PSLICE + p]);
        const float d = (DIAG[i] + DIAG[j] - 2.f * g) * (1.f / 16384.f);
        local = (tg[i] == tg[j]) ? d : fmaxf(1.f - d, 0.f);
    }
#pragma unroll
    for (int off = 32; off; off >>= 1) local += __shfl_down(local, off, 64);
    __shared__ float red[4];
    const int lane = t & 63, wid = t >> 6;
    if (lane == 0) red[wid] = local;
    __syncthreads();
    if (t == 0) LP[blockIdx.x] = red[0] + red[1] + red[2] + red[3];
}

__global__ void final_kernel(const float* __restrict__ LP, float* __restrict__ out) {
    const int t = threadIdx.x;
    float v = LP[t] + LP[t + 256] + LP[t + 512] + LP[t + 768];
#pragma unroll
    for (int off = 32; off; off >>= 1) v += __shfl_down(v, off, 64);
    __shared__ float red[4];
    if ((t & 63) == 0) red[t >> 6] = v;
    __syncthreads();
    if (t == 0) out[0] = (red[0] + red[1] + red[2] + red[3]) * (1.f / NPAIRS);
}

extern "C" void kernel_launch(void* const* d_in, const int* in_sizes, int n_in,
                              void* d_out, int out_size, void* d_ws, size_t ws_size,
                              hipStream_t stream) {
    const float* e  = (const float*)d_in[0];
    const float* a  = (const float*)d_in[1];
    const float* c  = (const float*)d_in[2];
    const int*   tg = (const int*)d_in[3];

    ushort* P    = (ushort*)d_ws;                                     // 48 MiB bf16 partials
    float*  DIAG = (float*)((char*)d_ws + (size_t)KSPLIT * PSLICE * 2);
    float*  LP   = DIAG + BSZ;
    float*  out  = (float*)d_out;

    gemm_kernel<<<dim3(NTILE * KSPLIT), dim3(256), 0, stream>>>(e, a, c, P);
    diag_kernel<<<dim3(2), dim3(256), 0, stream>>>(P, DIAG);
    pair_kernel<<<dim3(1024), dim3(256), 0, stream>>>(P, DIAG, tg, LP);
    final_kernel<<<dim3(1), dim3(256), 0, stream>>>(LP, out);
}